// Round 9
// baseline (54.442 us; speedup 1.0000x reference)
//
#include <hip/hip_runtime.h>

#define NB 8
#define NC 64
#define NH 256
#define NW 256
#define HW (NH*NW)
#define NFH 64
#define NFW 64
#define FHW (NFH*NFW)
#define NS 256
#define PPA 4096                 // pixels per role-A block (4 dense 1024-px windows)
#define NPA (HW/PPA)             // 16 pixel-blocks per image (role A)
#define PPB 1024                 // pixels per role-B block
#define NPB (HW/PPB)             // 64 pixel-blocks per image (role B)
#define NG 4                     // channel groups
#define CPG (NC/NG)              // 16 channels per group
#define NMAIN (NB*NPA*NG)        // 512 role-A blocks
#define NRB (NB*NPB)             // 512 role-B blocks

typedef float f32x4 __attribute__((ext_vector_type(4)));

// ---------------- K1: fused streaming kernel, 1024 blocks, split roles ----------------
// blocks [0, NMAIN): role A — 16-channel partial segment sums of input, 16 px/thread.
// blocks [NMAIN, NMAIN+NRB): role B — self-computes the <=3 fmean rows its pixels
//   touch (from feature), then counts + bilinear feature-mean segment sums.
__global__ __launch_bounds__(256) void
main_k(const float* __restrict__ input,
       const float* __restrict__ feature,
       const int* __restrict__ sp,
       float* __restrict__ part1,     // [NMAIN][NS]
       float* __restrict__ part2,     // [NRB][NS]
       float* __restrict__ partc,     // [NRB][NS]
       unsigned* __restrict__ counter) {
  __shared__ float s_bins[NS];
  __shared__ float s_fb[NS];
  __shared__ unsigned s_cnt[NS];
  __shared__ float s_frow[3][NFW];   // the (<=3) fmean rows a role-B block needs

  const int bid = blockIdx.x;
  const int tid = threadIdx.x;
  if (bid == 0 && tid == 0) *counter = 0u;   // arm finalize's last-block gate

  if (bid < NMAIN) {
    // ----- role A: 4096 px x 16 channels, four dense 1024-px windows -----
    const int g  = bid & (NG - 1);
    const int pb = (bid >> 2) & (NPA - 1);
    const int b  = bid >> 6;

    s_bins[tid] = 0.f;
    __syncthreads();

    const int base = pb * PPA;
    const float* ib = input + (size_t)(b * NC + g * CPG) * HW + base;
    const int o = tid * 4;
    f32x4 acc0 = (f32x4)(0.f);
    f32x4 acc1 = (f32x4)(0.f);
    f32x4 acc2 = (f32x4)(0.f);
    f32x4 acc3 = (f32x4)(0.f);
    #pragma unroll
    for (int c = 0; c < CPG; ++c) {
      const float* p = ib + (size_t)c * HW + o;
      acc0 += *reinterpret_cast<const f32x4*>(p);
      acc1 += *reinterpret_cast<const f32x4*>(p + 1024);
      acc2 += *reinterpret_cast<const f32x4*>(p + 2048);
      acc3 += *reinterpret_cast<const f32x4*>(p + 3072);
    }
    const int* spb = sp + (size_t)b * HW + base + o;
    const int4 id0 = *reinterpret_cast<const int4*>(spb);
    const int4 id1 = *reinterpret_cast<const int4*>(spb + 1024);
    const int4 id2 = *reinterpret_cast<const int4*>(spb + 2048);
    const int4 id3 = *reinterpret_cast<const int4*>(spb + 3072);
    const float s = 1.0f / NC;
    atomicAdd(&s_bins[id0.x], acc0.x * s);
    atomicAdd(&s_bins[id0.y], acc0.y * s);
    atomicAdd(&s_bins[id0.z], acc0.z * s);
    atomicAdd(&s_bins[id0.w], acc0.w * s);
    atomicAdd(&s_bins[id1.x], acc1.x * s);
    atomicAdd(&s_bins[id1.y], acc1.y * s);
    atomicAdd(&s_bins[id1.z], acc1.z * s);
    atomicAdd(&s_bins[id1.w], acc1.w * s);
    atomicAdd(&s_bins[id2.x], acc2.x * s);
    atomicAdd(&s_bins[id2.y], acc2.y * s);
    atomicAdd(&s_bins[id2.z], acc2.z * s);
    atomicAdd(&s_bins[id2.w], acc2.w * s);
    atomicAdd(&s_bins[id3.x], acc3.x * s);
    atomicAdd(&s_bins[id3.y], acc3.y * s);
    atomicAdd(&s_bins[id3.z], acc3.z * s);
    atomicAdd(&s_bins[id3.w], acc3.w * s);
    __syncthreads();

    part1[(size_t)bid * NS + tid] = s_bins[tid];
  } else {
    // ----- role B -----
    const int r  = bid - NMAIN;       // 0..511
    const int b  = r >> 6;
    const int pb = r & (NPB - 1);

    const int h0    = pb * 4;                       // first of 4 input rows
    const int y0min = (h0 * (NFH - 1)) / (NH - 1);  // lowest fmean row touched

    s_fb[tid] = 0.f;
    s_cnt[tid] = 0u;
    if (tid < 192) s_frow[tid >> 6][tid & 63] = 0.f;
    __syncthreads();

    // self-compute 3 fmean rows: thread = (channel-quarter q, px)
    {
      const int px = tid & 63;
      const int q  = tid >> 6;                      // 0..3
      const int r0 = min(y0min,     NFH - 1);
      const int r1 = min(y0min + 1, NFH - 1);
      const int r2 = min(y0min + 2, NFH - 1);
      const float* fb = feature + (size_t)(b * NC + q * 16) * FHW;
      float a0 = 0.f, a1 = 0.f, a2 = 0.f;
      #pragma unroll
      for (int c = 0; c < 16; ++c) {
        const float* fc = fb + (size_t)c * FHW;
        a0 += fc[r0 * NFW + px];
        a1 += fc[r1 * NFW + px];
        a2 += fc[r2 * NFW + px];
      }
      const float sc = 1.0f / NC;
      atomicAdd(&s_frow[0][px], a0 * sc);
      atomicAdd(&s_frow[1][px], a1 * sc);
      atomicAdd(&s_frow[2][px], a2 * sc);
    }
    __syncthreads();

    const int p0 = pb * PPB + tid * 4;
    const int4 idv = *reinterpret_cast<const int4*>(sp + (size_t)b * HW + p0);
    const int ids[4] = {idv.x, idv.y, idv.z, idv.w};

    const int h = p0 >> 8;            // row shared by the thread's 4 pixels
    const float yd = (float)h * (63.0f / 255.0f);
    const int y0 = (int)yd;
    const float wy = yd - (float)y0;
    const int y1 = min(y0 + 1, NFH - 1);
    const float* row0 = s_frow[y0 - y0min];
    const float* row1 = s_frow[y1 - y0min];

    #pragma unroll
    for (int i = 0; i < 4; ++i) {
      const int w = (p0 & 255) + i;
      const float xd = (float)w * (63.0f / 255.0f);
      const int x0 = (int)xd;
      const float wx = xd - (float)x0;
      const int x1 = min(x0 + 1, NFW - 1);
      float v0 = row0[x0] * (1.f - wy) + row1[x0] * wy;
      float v1 = row0[x1] * (1.f - wy) + row1[x1] * wy;
      float fv = v0 * (1.f - wx) + v1 * wx;
      atomicAdd(&s_fb[ids[i]], fv);
      atomicAdd(&s_cnt[ids[i]], 1u);
    }
    __syncthreads();

    part2[(size_t)r * NS + tid] = s_fb[tid];
    partc[(size_t)r * NS + tid] = (float)s_cnt[tid];
  }
}

// ---------------- K2: reduce partials -> means -> S x S loss; last block finishes ----
__global__ __launch_bounds__(256) void
finalize_k(const float* __restrict__ part1,
           const float* __restrict__ part2,
           const float* __restrict__ partc,
           const int* __restrict__ num,
           float* __restrict__ partial,
           unsigned* __restrict__ counter,
           float* __restrict__ out) {
  __shared__ float m1[NS];
  __shared__ float m2[NS];
  __shared__ float red[256];
  const int b = blockIdx.x;
  const int j = threadIdx.x;

  float s1 = 0.f;
  const float* p1 = part1 + (size_t)b * (NMAIN / NB) * NS + j;   // 64 blocks/image
  #pragma unroll 8
  for (int t = 0; t < NMAIN / NB; ++t) s1 += p1[(size_t)t * NS];

  float s2 = 0.f, c = 0.f;
  const float* p2 = part2 + (size_t)b * 64 * NS + j;
  const float* pc = partc + (size_t)b * 64 * NS + j;
  #pragma unroll 8
  for (int t = 0; t < 64; ++t) { s2 += p2[(size_t)t * NS]; c += pc[(size_t)t * NS]; }

  const int nb = num[b];
  float v1 = 0.f, v2 = 0.f;
  if (j < nb && c > 0.f) {
    float invc = 1.0f / c;
    v1 = s1 * invc;
    v2 = s2 * invc;
  }
  m1[j] = v1; m2[j] = v2;
  __syncthreads();

  float accum = 0.f;
  #pragma unroll 8
  for (int k = 0; k < NS; ++k) {
    accum += fabsf(fabsf(v1 - m1[k]) - fabsf(v2 - m2[k]));
  }
  red[j] = accum;
  __syncthreads();
  for (int st = 128; st > 0; st >>= 1) {
    if (j < st) red[j] += red[j + st];
    __syncthreads();
  }

  if (j == 0) {
    atomicExch(&partial[b], red[0]);        // device-scope coherent store
    __threadfence();
    unsigned old = atomicAdd(counter, 1u);
    if (old == NB - 1) {                    // last image block finishes the loss
      __threadfence();
      float sAll = 0.f;
      #pragma unroll
      for (int i = 0; i < NB; ++i) sAll += atomicAdd(&partial[i], 0.0f);
      out[0] = sAll / (float)(NB * NS * NS);
      *counter = 0u;
    }
  }
}

extern "C" void kernel_launch(void* const* d_in, const int* in_sizes, int n_in,
                              void* d_out, int out_size, void* d_ws, size_t ws_size,
                              hipStream_t stream) {
  const float* input   = (const float*)d_in[0];   // [8,64,256,256] f32
  const float* feature = (const float*)d_in[1];   // [8,64,64,64]   f32
  const int*   sp      = (const int*)d_in[2];     // [8,1,256,256]  int32
  const int*   num     = (const int*)d_in[3];     // [8]            int32
  float* out = (float*)d_out;

  float* ws      = (float*)d_ws;
  float*    part1   = ws;                                   // NMAIN*NS = 131072 floats
  float*    part2   = part1 + (size_t)NMAIN * NS;           // 131072
  float*    partc   = part2 + (size_t)NRB * NS;             // 131072
  float*    partial = partc + (size_t)NRB * NS;             // 8
  unsigned* counter = (unsigned*)(partial + 8);             // 1

  main_k<<<NMAIN + NRB, 256, 0, stream>>>(input, feature, sp, part1, part2, partc, counter);
  finalize_k<<<NB, 256, 0, stream>>>(part1, part2, partc, num, partial, counter, out);
}

// Round 10
// 53.855 us; speedup vs baseline: 1.0109x; 1.0109x over previous
//
#include <hip/hip_runtime.h>

#define NB 8
#define NC 64
#define NH 256
#define NW 256
#define HW (NH*NW)
#define NFH 64
#define NFW 64
#define FHW (NFH*NFW)
#define NS 256
#define PPA 2048                 // pixels per role-A block (R8 optimum)
#define NPA (HW/PPA)             // 32 pixel-blocks per image (role A)
#define PPB 1024                 // pixels per role-B block
#define NPB (HW/PPB)             // 64 pixel-blocks per image (role B)
#define NG 4                     // channel groups
#define CPG (NC/NG)              // 16 channels per group
#define NMAIN (NB*NPA*NG)        // 1024 role-A blocks
#define NRB (NB*NPB)             // 512 role-B blocks

typedef float f32x4 __attribute__((ext_vector_type(4)));

// ---------------- K0: zero the global accumulators (1 block) ----------------
__global__ __launch_bounds__(256) void zero_k(float* __restrict__ acc /* 3*NB*NS + 8 + 1 */) {
  for (int i = threadIdx.x; i < 3 * NB * NS + 9; i += 256) acc[i] = 0.f;
}

// ---------------- K1: fused streaming kernel, 1536 blocks, split roles ----------------
// blocks [0, NMAIN): role A — 16-channel partial segment sums of input, 8 px/thread,
//   flushed with one global atomicAdd per bin.
// blocks [NMAIN, NMAIN+NRB): role B — self-computes the <=3 fmean rows its pixels
//   touch (from feature), then counts + bilinear feature-mean segment sums.
__global__ __launch_bounds__(256) void
main_k(const float* __restrict__ input,
       const float* __restrict__ feature,
       const int* __restrict__ sp,
       float* __restrict__ sum1,      // [NB][NS] global atomic accumulators
       float* __restrict__ sum2,      // [NB][NS]
       float* __restrict__ cntf) {    // [NB][NS]
  __shared__ float s_bins[NS];
  __shared__ float s_fb[NS];
  __shared__ unsigned s_cnt[NS];
  __shared__ float s_frow[3][NFW];   // the (<=3) fmean rows a role-B block needs

  const int bid = blockIdx.x;
  const int tid = threadIdx.x;

  if (bid < NMAIN) {
    // ----- role A: 2048 px x 16 channels, two dense 1024-px windows -----
    const int g  = bid & (NG - 1);
    const int pb = (bid >> 2) & (NPA - 1);
    const int b  = bid >> 7;

    s_bins[tid] = 0.f;
    __syncthreads();

    const int base = pb * PPA;
    const float* ib = input + (size_t)(b * NC + g * CPG) * HW + base;
    const int o = tid * 4;
    f32x4 accA = (f32x4)(0.f);
    f32x4 accB = (f32x4)(0.f);
    #pragma unroll
    for (int c = 0; c < CPG; ++c) {
      const float* p = ib + (size_t)c * HW + o;
      accA += *reinterpret_cast<const f32x4*>(p);
      accB += *reinterpret_cast<const f32x4*>(p + 1024);
    }
    const int* spb = sp + (size_t)b * HW + base + o;
    const int4 idvA = *reinterpret_cast<const int4*>(spb);
    const int4 idvB = *reinterpret_cast<const int4*>(spb + 1024);
    const float s = 1.0f / NC;
    atomicAdd(&s_bins[idvA.x], accA.x * s);
    atomicAdd(&s_bins[idvA.y], accA.y * s);
    atomicAdd(&s_bins[idvA.z], accA.z * s);
    atomicAdd(&s_bins[idvA.w], accA.w * s);
    atomicAdd(&s_bins[idvB.x], accB.x * s);
    atomicAdd(&s_bins[idvB.y], accB.y * s);
    atomicAdd(&s_bins[idvB.z], accB.z * s);
    atomicAdd(&s_bins[idvB.w], accB.w * s);
    __syncthreads();

    atomicAdd(&sum1[b * NS + tid], s_bins[tid]);
  } else {
    // ----- role B -----
    const int r  = bid - NMAIN;       // 0..511
    const int b  = r >> 6;
    const int pb = r & (NPB - 1);

    const int h0    = pb * 4;                       // first of 4 input rows
    const int y0min = (h0 * (NFH - 1)) / (NH - 1);  // lowest fmean row touched

    s_fb[tid] = 0.f;
    s_cnt[tid] = 0u;
    if (tid < 192) s_frow[tid >> 6][tid & 63] = 0.f;
    __syncthreads();

    // self-compute 3 fmean rows: thread = (channel-quarter q, px)
    {
      const int px = tid & 63;
      const int q  = tid >> 6;                      // 0..3
      const int r0 = min(y0min,     NFH - 1);
      const int r1 = min(y0min + 1, NFH - 1);
      const int r2 = min(y0min + 2, NFH - 1);
      const float* fb = feature + (size_t)(b * NC + q * 16) * FHW;
      float a0 = 0.f, a1 = 0.f, a2 = 0.f;
      #pragma unroll
      for (int c = 0; c < 16; ++c) {
        const float* fc = fb + (size_t)c * FHW;
        a0 += fc[r0 * NFW + px];
        a1 += fc[r1 * NFW + px];
        a2 += fc[r2 * NFW + px];
      }
      const float sc = 1.0f / NC;
      atomicAdd(&s_frow[0][px], a0 * sc);
      atomicAdd(&s_frow[1][px], a1 * sc);
      atomicAdd(&s_frow[2][px], a2 * sc);
    }
    __syncthreads();

    const int p0 = pb * PPB + tid * 4;
    const int4 idv = *reinterpret_cast<const int4*>(sp + (size_t)b * HW + p0);
    const int ids[4] = {idv.x, idv.y, idv.z, idv.w};

    const int h = p0 >> 8;            // row shared by the thread's 4 pixels
    const float yd = (float)h * (63.0f / 255.0f);
    const int y0 = (int)yd;
    const float wy = yd - (float)y0;
    const int y1 = min(y0 + 1, NFH - 1);
    const float* row0 = s_frow[y0 - y0min];
    const float* row1 = s_frow[y1 - y0min];

    #pragma unroll
    for (int i = 0; i < 4; ++i) {
      const int w = (p0 & 255) + i;
      const float xd = (float)w * (63.0f / 255.0f);
      const int x0 = (int)xd;
      const float wx = xd - (float)x0;
      const int x1 = min(x0 + 1, NFW - 1);
      float v0 = row0[x0] * (1.f - wy) + row1[x0] * wy;
      float v1 = row0[x1] * (1.f - wy) + row1[x1] * wy;
      float fv = v0 * (1.f - wx) + v1 * wx;
      atomicAdd(&s_fb[ids[i]], fv);
      atomicAdd(&s_cnt[ids[i]], 1u);
    }
    __syncthreads();

    atomicAdd(&sum2[b * NS + tid], s_fb[tid]);
    atomicAdd(&cntf[b * NS + tid], (float)s_cnt[tid]);
  }
}

// ---------------- K2: means -> S x S loss; last block finishes ----------------
__global__ __launch_bounds__(256) void
finalize_k(const float* __restrict__ sum1,
           const float* __restrict__ sum2,
           const float* __restrict__ cntf,
           const int* __restrict__ num,
           float* __restrict__ partial,
           unsigned* __restrict__ counter,
           float* __restrict__ out) {
  __shared__ float m1[NS];
  __shared__ float m2[NS];
  __shared__ float red[256];
  const int b = blockIdx.x;
  const int j = threadIdx.x;

  const float s1 = sum1[b * NS + j];
  const float s2 = sum2[b * NS + j];
  const float c  = cntf[b * NS + j];

  const int nb = num[b];
  float v1 = 0.f, v2 = 0.f;
  if (j < nb && c > 0.f) {
    float invc = 1.0f / c;
    v1 = s1 * invc;
    v2 = s2 * invc;
  }
  m1[j] = v1; m2[j] = v2;
  __syncthreads();

  float accum = 0.f;
  #pragma unroll 8
  for (int k = 0; k < NS; ++k) {
    accum += fabsf(fabsf(v1 - m1[k]) - fabsf(v2 - m2[k]));
  }
  red[j] = accum;
  __syncthreads();
  for (int st = 128; st > 0; st >>= 1) {
    if (j < st) red[j] += red[j + st];
    __syncthreads();
  }

  if (j == 0) {
    atomicExch(&partial[b], red[0]);        // device-scope coherent store
    __threadfence();
    unsigned old = atomicAdd(counter, 1u);
    if (old == NB - 1) {                    // last image block finishes the loss
      __threadfence();
      float sAll = 0.f;
      #pragma unroll
      for (int i = 0; i < NB; ++i) sAll += atomicAdd(&partial[i], 0.0f);
      out[0] = sAll / (float)(NB * NS * NS);
    }
  }
}

extern "C" void kernel_launch(void* const* d_in, const int* in_sizes, int n_in,
                              void* d_out, int out_size, void* d_ws, size_t ws_size,
                              hipStream_t stream) {
  const float* input   = (const float*)d_in[0];   // [8,64,256,256] f32
  const float* feature = (const float*)d_in[1];   // [8,64,64,64]   f32
  const int*   sp      = (const int*)d_in[2];     // [8,1,256,256]  int32
  const int*   num     = (const int*)d_in[3];     // [8]            int32
  float* out = (float*)d_out;

  float* ws = (float*)d_ws;
  float*    sum1    = ws;                         // 2048
  float*    sum2    = ws + NB * NS;               // 2048
  float*    cntf    = ws + 2 * NB * NS;           // 2048
  float*    partial = ws + 3 * NB * NS;           // 8
  unsigned* counter = (unsigned*)(partial + 8);   // 1  (zeroed by zero_k)

  zero_k<<<1, 256, 0, stream>>>(ws);
  main_k<<<NMAIN + NRB, 256, 0, stream>>>(input, feature, sp, sum1, sum2, cntf);
  finalize_k<<<NB, 256, 0, stream>>>(sum1, sum2, cntf, num, partial, counter, out);
}